// Round 1
// baseline (1759.834 us; speedup 1.0000x reference)
//
#include <hip/hip_runtime.h>
#include <math.h>

#define BB 2
#define SS 2048
#define DD 2048
#define NR (BB*(SS-1))      // 4094 rows after shift
#define HEADM 1003          // shortlist 1000 + 3 cluster logits

// ---------------- block reduce helpers (blockDim = 256) ----------------
__device__ inline float block_sum256(float v) {
    __shared__ float tmp[4];
    #pragma unroll
    for (int o = 32; o > 0; o >>= 1) v += __shfl_down(v, o, 64);
    int lane = threadIdx.x & 63, w = threadIdx.x >> 6;
    if (lane == 0) tmp[w] = v;
    __syncthreads();
    float r = tmp[0] + tmp[1] + tmp[2] + tmp[3];
    __syncthreads();
    return r;
}

__device__ inline float block_max256(float v) {
    __shared__ float tmp[4];
    #pragma unroll
    for (int o = 32; o > 0; o >>= 1) v = fmaxf(v, __shfl_down(v, o, 64));
    int lane = threadIdx.x & 63, w = threadIdx.x >> 6;
    if (lane == 0) tmp[w] = v;
    __syncthreads();
    float r = fmaxf(fmaxf(tmp[0], tmp[1]), fmaxf(tmp[2], tmp[3]));
    __syncthreads();
    return r;
}

// ---------------- LayerNorm over D for the N shifted rows ----------------
__global__ __launch_bounds__(256) void ln_kernel(const float* __restrict__ x,
        const float* __restrict__ gamma, const float* __restrict__ beta,
        float* __restrict__ h) {
    int n = blockIdx.x;                 // 0..NR-1
    int b = n / (SS - 1), t = n % (SS - 1);
    const float4* xr = (const float4*)(x + (size_t)(b * SS + t) * DD);
    int tid = threadIdx.x;
    float4 a = xr[tid];
    float4 c = xr[tid + 256];
    float sum = a.x + a.y + a.z + a.w + c.x + c.y + c.z + c.w;
    sum = block_sum256(sum);
    float mu = sum * (1.0f / DD);
    float d0 = a.x - mu, d1 = a.y - mu, d2 = a.z - mu, d3 = a.w - mu;
    float d4 = c.x - mu, d5 = c.y - mu, d6 = c.z - mu, d7 = c.w - mu;
    float sq = d0*d0 + d1*d1 + d2*d2 + d3*d3 + d4*d4 + d5*d5 + d6*d6 + d7*d7;
    sq = block_sum256(sq);
    float rstd = rsqrtf(sq * (1.0f / DD) + 1e-5f);
    const float4* g4 = (const float4*)gamma;
    const float4* be4 = (const float4*)beta;
    float4 g1 = g4[tid], g2 = g4[tid + 256];
    float4 b1 = be4[tid], b2 = be4[tid + 256];
    float4 o1, o2;
    o1.x = d0 * rstd * g1.x + b1.x;  o1.y = d1 * rstd * g1.y + b1.y;
    o1.z = d2 * rstd * g1.z + b1.z;  o1.w = d3 * rstd * g1.w + b1.w;
    o2.x = d4 * rstd * g2.x + b2.x;  o2.y = d5 * rstd * g2.y + b2.y;
    o2.z = d6 * rstd * g2.z + b2.z;  o2.w = d7 * rstd * g2.w + b2.w;
    float4* hr = (float4*)(h + (size_t)n * DD);
    hr[tid] = o1;
    hr[tid + 256] = o2;
}

// ---------------- C[N x M] = A[N x K] * W[M x K]^T, fp32, 64x64 tile ----------------
__global__ __launch_bounds__(256) void gemm_nt(const float* __restrict__ A,
        const float* __restrict__ W, float* __restrict__ C,
        int Nrows, int M, int K) {
    __shared__ __align__(16) float As[16][68];   // [k][row], +4 pad keeps 16B align & 2-way-max conflicts
    __shared__ __align__(16) float Wt[16][68];   // [k][col]
    int tid = threadIdx.x;
    int tx = tid & 15, ty = tid >> 4;
    int row0 = blockIdx.y * 64, col0 = blockIdx.x * 64;
    float acc[4][4] = {};
    int lr = tid >> 2;             // 0..63 tile row
    int c4 = (tid & 3) * 4;        // k offset within 16
    for (int k0 = 0; k0 < K; k0 += 16) {
        int gr = row0 + lr, gm = col0 + lr;
        float4 av = make_float4(0.f, 0.f, 0.f, 0.f);
        float4 wv = make_float4(0.f, 0.f, 0.f, 0.f);
        if (gr < Nrows) av = *(const float4*)(A + (size_t)gr * K + k0 + c4);
        if (gm < M)     wv = *(const float4*)(W + (size_t)gm * K + k0 + c4);
        __syncthreads();           // previous iteration's compute done
        As[c4 + 0][lr] = av.x; As[c4 + 1][lr] = av.y; As[c4 + 2][lr] = av.z; As[c4 + 3][lr] = av.w;
        Wt[c4 + 0][lr] = wv.x; Wt[c4 + 1][lr] = wv.y; Wt[c4 + 2][lr] = wv.z; Wt[c4 + 3][lr] = wv.w;
        __syncthreads();
        #pragma unroll
        for (int kk = 0; kk < 16; ++kk) {
            float4 a4 = *(const float4*)&As[kk][ty * 4];
            float4 w4 = *(const float4*)&Wt[kk][tx * 4];
            float ar[4] = {a4.x, a4.y, a4.z, a4.w};
            float wr[4] = {w4.x, w4.y, w4.z, w4.w};
            #pragma unroll
            for (int i = 0; i < 4; ++i)
                #pragma unroll
                for (int j = 0; j < 4; ++j)
                    acc[i][j] = fmaf(ar[i], wr[j], acc[i][j]);
        }
    }
    int rbase = row0 + ty * 4, cbase = col0 + tx * 4;
    #pragma unroll
    for (int i = 0; i < 4; ++i) {
        int gr = rbase + i;
        if (gr >= Nrows) continue;
        #pragma unroll
        for (int j = 0; j < 4; ++j) {
            int gc = cbase + j;
            if (gc < M) C[(size_t)gr * M + gc] = acc[i][j];
        }
    }
}

// ---------------- head: per-row logsumexp + gathers ----------------
// aux[n*8+0]=target logit, +1=lse, +2..4=cluster logits (cols 1000..1002)
__global__ __launch_bounds__(256) void head_reduce(const float* __restrict__ logits,
        const int* __restrict__ targets, float* __restrict__ aux) {
    int n = blockIdx.x;
    const float* lr = logits + (size_t)n * HEADM;
    int tid = threadIdx.x;
    float mx = -1e30f;
    for (int j = tid; j < HEADM; j += 256) mx = fmaxf(mx, lr[j]);
    mx = block_max256(mx);
    float s = 0.f;
    for (int j = tid; j < HEADM; j += 256) s += __expf(lr[j] - mx);
    s = block_sum256(s);
    if (tid == 0) {
        int b = n / (SS - 1), t = n % (SS - 1);
        int lbl = targets[b * SS + t + 1];
        int ti = lbl < 1000 ? lbl : 999;
        float lse = mx + logf(s);
        aux[n * 8 + 0] = lr[ti];
        aux[n * 8 + 1] = lse;
        aux[n * 8 + 2] = lr[1000];
        aux[n * 8 + 3] = lr[1001];
        aux[n * 8 + 4] = lr[1002];
    }
}

// ---------------- fused tail: logits + online logsumexp + target gather ----------------
template<int HSZ>
__global__ __launch_bounds__(256) void tail_kernel(
        const float* __restrict__ proj,   // [NR][HSZ]
        const float* __restrict__ w2,     // [osz][HSZ]
        const int* __restrict__ targets,
        int osz, int low,
        float* __restrict__ tgt_out, float* __restrict__ lse_out) {
    constexpr int R = 4;
    __shared__ __align__(16) float pl[R][HSZ];
    __shared__ float ttgt[R];
    __shared__ float wm[4][R], wsum[4][R];
    int r0 = blockIdx.x * R;
    int tid = threadIdx.x;
    for (int idx = tid; idx < R * HSZ; idx += 256) {
        int r = idx / HSZ, cc = idx % HSZ;
        int gr = r0 + r;
        pl[r][cc] = (gr < NR) ? proj[(size_t)gr * HSZ + cc] : 0.f;
    }
    if (tid < R) ttgt[tid] = 0.f;
    int relc[R];
    #pragma unroll
    for (int r = 0; r < R; ++r) {
        int gr = r0 + r;
        if (gr < NR) {
            int b = gr / (SS - 1), t = gr % (SS - 1);
            int lbl = targets[b * SS + t + 1];
            int rel = lbl - low;
            relc[r] = rel < 0 ? 0 : (rel > osz - 1 ? osz - 1 : rel);
        } else relc[r] = -1;
    }
    __syncthreads();
    float m[R], s[R];
    #pragma unroll
    for (int r = 0; r < R; ++r) { m[r] = -1e30f; s[r] = 0.f; }
    for (int o = tid; o < osz; o += 256) {
        const float* wr = w2 + (size_t)o * HSZ;
        float acc[R] = {0.f, 0.f, 0.f, 0.f};
        for (int k = 0; k < HSZ; k += 4) {
            float4 wv = *(const float4*)(wr + k);
            #pragma unroll
            for (int r = 0; r < R; ++r) {
                float4 p = *(const float4*)(&pl[r][k]);   // broadcast across lanes: conflict-free
                acc[r] = fmaf(wv.x, p.x, acc[r]);
                acc[r] = fmaf(wv.y, p.y, acc[r]);
                acc[r] = fmaf(wv.z, p.z, acc[r]);
                acc[r] = fmaf(wv.w, p.w, acc[r]);
            }
        }
        #pragma unroll
        for (int r = 0; r < R; ++r) {
            float v = acc[r];
            float nm = fmaxf(m[r], v);
            s[r] = s[r] * __expf(m[r] - nm) + __expf(v - nm);
            m[r] = nm;
            if (o == relc[r]) ttgt[r] = v;
        }
    }
    #pragma unroll
    for (int off = 32; off > 0; off >>= 1) {
        #pragma unroll
        for (int r = 0; r < R; ++r) {
            float om = __shfl_down(m[r], off, 64);
            float os = __shfl_down(s[r], off, 64);
            float M2 = fmaxf(m[r], om);
            s[r] = s[r] * __expf(m[r] - M2) + os * __expf(om - M2);
            m[r] = M2;
        }
    }
    int lane = tid & 63, wid = tid >> 6;
    if (lane == 0) {
        #pragma unroll
        for (int r = 0; r < R; ++r) { wm[wid][r] = m[r]; wsum[wid][r] = s[r]; }
    }
    __syncthreads();
    if (tid == 0) {
        for (int r = 0; r < R; ++r) {
            int gr = r0 + r;
            if (gr >= NR) continue;
            float M2 = wm[0][r], S2 = wsum[0][r];
            for (int w = 1; w < 4; ++w) {
                float M3 = fmaxf(M2, wm[w][r]);
                S2 = S2 * __expf(M2 - M3) + wsum[w][r] * __expf(wm[w][r] - M3);
                M2 = M3;
            }
            lse_out[gr] = M2 + logf(S2);
            tgt_out[gr] = ttgt[r];
        }
    }
}

// ---------------- final: assemble per-row logprob, mean, negate ----------------
__global__ __launch_bounds__(256) void final_kernel(const float* __restrict__ aux,
        const int* __restrict__ targets,
        const float* __restrict__ tt0, const float* __restrict__ tl0,
        const float* __restrict__ tt1, const float* __restrict__ tl1,
        const float* __restrict__ tt2, const float* __restrict__ tl2,
        float* __restrict__ out) {
    float local = 0.f;
    for (int n = threadIdx.x; n < NR; n += 256) {
        int b = n / (SS - 1), t = n % (SS - 1);
        int lbl = targets[b * SS + t + 1];
        float lse = aux[n * 8 + 1];
        float o;
        if (lbl < 1000)      o = aux[n * 8 + 0] - lse;
        else if (lbl < 2000) o = (aux[n * 8 + 2] - lse) + (tt0[n] - tl0[n]);
        else if (lbl < 5000) o = (aux[n * 8 + 3] - lse) + (tt1[n] - tl1[n]);
        else                 o = (aux[n * 8 + 4] - lse) + (tt2[n] - tl2[n]);
        local += o;
    }
    float tot = block_sum256(local);
    if (threadIdx.x == 0) out[0] = -tot / (float)NR;
}

extern "C" void kernel_launch(void* const* d_in, const int* in_sizes, int n_in,
                              void* d_out, int out_size, void* d_ws, size_t ws_size,
                              hipStream_t stream) {
    const float* x      = (const float*)d_in[0];
    const int*   targets= (const int*)d_in[1];
    const float* gamma  = (const float*)d_in[2];
    const float* beta   = (const float*)d_in[3];
    const float* head_w = (const float*)d_in[4];
    const float* t1_w1  = (const float*)d_in[5];
    const float* t1_w2  = (const float*)d_in[6];
    const float* t2_w1  = (const float*)d_in[7];
    const float* t2_w2  = (const float*)d_in[8];
    const float* t3_w1  = (const float*)d_in[9];
    const float* t3_w2  = (const float*)d_in[10];

    float* ws = (float*)d_ws;
    size_t off = 0;
    auto alloc = [&](size_t n) { float* p = ws + off; off += (n + 3) & ~(size_t)3; return p; };
    float* h   = alloc((size_t)NR * DD);        // 33.5 MB
    float* hl  = alloc((size_t)NR * HEADM);     // 16.4 MB
    float* p1  = alloc((size_t)NR * 512);       // 8.4 MB
    float* p2  = alloc((size_t)NR * 128);       // 2.1 MB
    float* p3  = alloc((size_t)NR * 32);        // 0.5 MB
    float* aux = alloc((size_t)NR * 8);
    float* tt0 = alloc(NR); float* tl0 = alloc(NR);
    float* tt1 = alloc(NR); float* tl1 = alloc(NR);
    float* tt2 = alloc(NR); float* tl2 = alloc(NR);
    (void)ws_size; (void)in_sizes; (void)n_in; (void)out_size;

    ln_kernel<<<NR, 256, 0, stream>>>(x, gamma, beta, h);
    gemm_nt<<<dim3(16, 64), 256, 0, stream>>>(h, head_w, hl, NR, HEADM, DD);
    gemm_nt<<<dim3(8, 64),  256, 0, stream>>>(h, t1_w1, p1, NR, 512, DD);
    gemm_nt<<<dim3(2, 64),  256, 0, stream>>>(h, t2_w1, p2, NR, 128, DD);
    gemm_nt<<<dim3(1, 64),  256, 0, stream>>>(h, t3_w1, p3, NR, 32, DD);
    head_reduce<<<NR, 256, 0, stream>>>(hl, targets, aux);
    tail_kernel<512><<<(NR + 3) / 4, 256, 0, stream>>>(p1, t1_w2, targets, 1000, 1000, tt0, tl0);
    tail_kernel<128><<<(NR + 3) / 4, 256, 0, stream>>>(p2, t2_w2, targets, 3000, 2000, tt1, tl1);
    tail_kernel<32> <<<(NR + 3) / 4, 256, 0, stream>>>(p3, t3_w2, targets, 27000, 5000, tt2, tl2);
    final_kernel<<<1, 256, 0, stream>>>(aux, targets, tt0, tl0, tt1, tl1, tt2, tl2, (float*)d_out);
}

// Round 2
// 346.010 us; speedup vs baseline: 5.0861x; 5.0861x over previous
//
#include <hip/hip_runtime.h>
#include <hip/hip_bf16.h>
#include <math.h>

#define BB 2
#define SS 2048
#define DD 2048
#define NR (BB*(SS-1))      // 4094 valid rows
#define NRP 4096            // padded rows
// mega-C column layout (one GEMM produces head logits + all three projections)
#define MC_P1   1024
#define MC_P2   1536
#define MC_P3   1664
#define MC_LD   1792

typedef short  bh8   __attribute__((ext_vector_type(8)));   // 8 x bf16 (4 VGPRs)
typedef float  f32x4 __attribute__((ext_vector_type(4)));

// ---------------- block reduce helpers (blockDim = 256) ----------------
__device__ inline float block_sum256(float v) {
    __shared__ float tmp[4];
    #pragma unroll
    for (int o = 32; o > 0; o >>= 1) v += __shfl_down(v, o, 64);
    int lane = threadIdx.x & 63, w = threadIdx.x >> 6;
    if (lane == 0) tmp[w] = v;
    __syncthreads();
    float r = tmp[0] + tmp[1] + tmp[2] + tmp[3];
    __syncthreads();
    return r;
}

__device__ inline float block_max256(float v) {
    __shared__ float tmp[4];
    #pragma unroll
    for (int o = 32; o > 0; o >>= 1) v = fmaxf(v, __shfl_down(v, o, 64));
    int lane = threadIdx.x & 63, w = threadIdx.x >> 6;
    if (lane == 0) tmp[w] = v;
    __syncthreads();
    float r = fmaxf(fmaxf(tmp[0], tmp[1]), fmaxf(tmp[2], tmp[3]));
    __syncthreads();
    return r;
}

// ---------------- LayerNorm -> bf16 h (rows NR..NRP-1 zeroed) ----------------
__global__ __launch_bounds__(256) void ln_kernel(const float* __restrict__ x,
        const float* __restrict__ gamma, const float* __restrict__ beta,
        __hip_bfloat16* __restrict__ h) {
    int n = blockIdx.x;                 // 0..NRP-1
    int tid = threadIdx.x;
    __hip_bfloat16* hr = h + (size_t)n * DD;
    if (n >= NR) {                      // pad rows: zero (block-uniform branch)
        uint4 z = make_uint4(0, 0, 0, 0);
        *(uint4*)(hr + tid * 8) = z;
        return;
    }
    int b = n / (SS - 1), t = n % (SS - 1);
    const float4* xr = (const float4*)(x + (size_t)(b * SS + t) * DD);
    float4 a = xr[tid * 2];             // elements 8*tid .. 8*tid+7
    float4 c = xr[tid * 2 + 1];
    float sum = a.x + a.y + a.z + a.w + c.x + c.y + c.z + c.w;
    sum = block_sum256(sum);
    float mu = sum * (1.0f / DD);
    float d[8] = {a.x - mu, a.y - mu, a.z - mu, a.w - mu,
                  c.x - mu, c.y - mu, c.z - mu, c.w - mu};
    float sq = 0.f;
    #pragma unroll
    for (int i = 0; i < 8; ++i) sq += d[i] * d[i];
    sq = block_sum256(sq);
    float rstd = rsqrtf(sq * (1.0f / DD) + 1e-5f);
    const float4* g4 = (const float4*)gamma;
    const float4* be4 = (const float4*)beta;
    float4 g1 = g4[tid * 2], g2 = g4[tid * 2 + 1];
    float4 b1 = be4[tid * 2], b2 = be4[tid * 2 + 1];
    float gg[8] = {g1.x, g1.y, g1.z, g1.w, g2.x, g2.y, g2.z, g2.w};
    float bb[8] = {b1.x, b1.y, b1.z, b1.w, b2.x, b2.y, b2.z, b2.w};
    __align__(16) __hip_bfloat16 ob[8];
    #pragma unroll
    for (int i = 0; i < 8; ++i) ob[i] = __float2bfloat16(d[i] * rstd * gg[i] + bb[i]);
    *(uint4*)(hr + tid * 8) = *(uint4*)ob;
}

// ---------------- fp32 -> bf16 cast with zero padding ----------------
__global__ __launch_bounds__(256) void cast_pad(const float* __restrict__ src,
        __hip_bfloat16* __restrict__ dst, int n_src, int n_tot) {
    int i = (blockIdx.x * 256 + threadIdx.x) * 4;
    if (i >= n_tot) return;
    float4 v = make_float4(0.f, 0.f, 0.f, 0.f);
    if (i + 4 <= n_src) v = *(const float4*)(src + i);
    __align__(8) __hip_bfloat16 o[4] = {
        __float2bfloat16(v.x), __float2bfloat16(v.y),
        __float2bfloat16(v.z), __float2bfloat16(v.w)};
    *(uint2*)(dst + i) = *(uint2*)o;
}

// ---------------- bf16 MFMA GEMM: C[128y x 128x] = A[.,K](lda) * W[.,K]^T ----------------
// m97 structure: 128x128 tile, BK=32, global_load_lds width-16, 4 waves (64x64 each)
__global__ __launch_bounds__(256) void gemm_bf16(
        const __hip_bfloat16* __restrict__ A, int lda,
        const __hip_bfloat16* __restrict__ W,        // [Mpad][K], ldw == K
        __hip_bfloat16* __restrict__ C, int ldc,
        int K) {
    __shared__ __align__(16) __hip_bfloat16 As[128 * 32];
    __shared__ __align__(16) __hip_bfloat16 Ws[128 * 32];
    int tid = threadIdx.x;
    int wv = tid >> 6, lane = tid & 63;
    size_t row0 = (size_t)blockIdx.y * 128;
    size_t col0 = (size_t)blockIdx.x * 128;
    int wrow = (wv >> 1) * 64, wcol = (wv & 1) * 64;
    f32x4 acc[4][4];
    #pragma unroll
    for (int i = 0; i < 4; ++i)
        #pragma unroll
        for (int j = 0; j < 4; ++j) acc[i][j] = (f32x4){0.f, 0.f, 0.f, 0.f};

    int sr = lane >> 2;           // row within 16-row chunk
    int sk = (lane & 3) * 8;      // k element offset (8 bf16 = 16 B)
    int mrow = lane & 15;
    int q16 = (lane >> 4) * 16;   // k-chunk byte offset for frag reads

    for (int k0 = 0; k0 < K; k0 += 32) {
        __syncthreads();          // prior iter's ds_reads done before overwrite
        #pragma unroll
        for (int i = 0; i < 2; ++i) {
            int chunk = wv * 2 + i;            // 0..7 -> rows chunk*16..+15
            int r = chunk * 16 + sr;
            const void* ga = A + (row0 + r) * lda + k0 + sk;
            const void* gw = W + (col0 + r) * (size_t)K + k0 + sk;
            void* la = (char*)As + chunk * 1024 + lane * 16;
            void* lw = (char*)Ws + chunk * 1024 + lane * 16;
            __builtin_amdgcn_global_load_lds(
                (const __attribute__((address_space(1))) void*)ga,
                (__attribute__((address_space(3))) void*)la, 16, 0, 0);
            __builtin_amdgcn_global_load_lds(
                (const __attribute__((address_space(1))) void*)gw,
                (__attribute__((address_space(3))) void*)lw, 16, 0, 0);
        }
        __syncthreads();          // implies vmcnt(0): staging complete
        bh8 af[4], bfr[4];
        #pragma unroll
        for (int t = 0; t < 4; ++t) {
            af[t]  = *(const bh8*)((const char*)As + (wrow + t * 16 + mrow) * 64 + q16);
            bfr[t] = *(const bh8*)((const char*)Ws + (wcol + t * 16 + mrow) * 64 + q16);
        }
        #pragma unroll
        for (int i = 0; i < 4; ++i)
            #pragma unroll
            for (int j = 0; j < 4; ++j)
                acc[i][j] = __builtin_amdgcn_mfma_f32_16x16x32_bf16(af[i], bfr[j], acc[i][j], 0, 0, 0);
    }
    // C/D layout: col = lane&15, row = (lane>>4)*4 + reg  [m89/m91 verified]
    int ccol = lane & 15;
    int crow = (lane >> 4) * 4;
    #pragma unroll
    for (int i = 0; i < 4; ++i) {
        size_t gr0 = row0 + wrow + i * 16 + crow;
        #pragma unroll
        for (int j = 0; j < 4; ++j) {
            size_t gc = col0 + wcol + j * 16 + ccol;
            #pragma unroll
            for (int r = 0; r < 4; ++r)
                C[(gr0 + r) * ldc + gc] = __float2bfloat16(acc[i][j][r]);
        }
    }
}

// ---------------- head: per-row logsumexp over 1003 + gathers ----------------
__global__ __launch_bounds__(256) void head_reduce(const __hip_bfloat16* __restrict__ mega,
        const int* __restrict__ targets, float* __restrict__ aux) {
    int n = blockIdx.x;
    const __hip_bfloat16* lr = mega + (size_t)n * MC_LD;
    int tid = threadIdx.x;
    float mx = -1e30f;
    for (int j = tid; j < 1003; j += 256) mx = fmaxf(mx, __bfloat162float(lr[j]));
    mx = block_max256(mx);
    float s = 0.f;
    for (int j = tid; j < 1003; j += 256) s += __expf(__bfloat162float(lr[j]) - mx);
    s = block_sum256(s);
    if (tid == 0) {
        int b = n / (SS - 1), t = n % (SS - 1);
        int lbl = targets[b * SS + t + 1];
        int ti = lbl < 1000 ? lbl : 999;
        aux[n * 8 + 0] = __bfloat162float(lr[ti]);
        aux[n * 8 + 1] = mx + logf(s);
        aux[n * 8 + 2] = __bfloat162float(lr[1000]);
        aux[n * 8 + 3] = __bfloat162float(lr[1001]);
        aux[n * 8 + 4] = __bfloat162float(lr[1002]);
    }
}

// ---------------- tail 1/2: per-row logsumexp + target gather over materialized logits ----------------
__global__ __launch_bounds__(256) void tail_reduce(const __hip_bfloat16* __restrict__ logits,
        int ldc, int osz, int low, const int* __restrict__ targets,
        float* __restrict__ tgt_out, float* __restrict__ lse_out) {
    int n = blockIdx.x;
    const __hip_bfloat16* lr = logits + (size_t)n * ldc;
    int tid = threadIdx.x;
    float mx = -1e30f;
    for (int j = tid; j < osz; j += 256) mx = fmaxf(mx, __bfloat162float(lr[j]));
    mx = block_max256(mx);
    float s = 0.f;
    for (int j = tid; j < osz; j += 256) s += __expf(__bfloat162float(lr[j]) - mx);
    s = block_sum256(s);
    if (tid == 0) {
        int b = n / (SS - 1), t = n % (SS - 1);
        int lbl = targets[b * SS + t + 1];
        int rel = lbl - low;
        rel = rel < 0 ? 0 : (rel > osz - 1 ? osz - 1 : rel);
        tgt_out[n] = __bfloat162float(lr[rel]);
        lse_out[n] = mx + logf(s);
    }
}

// ---------------- tail 3 fused: MFMA (K=32) + online LSE, no logit materialization ----------------
// grid 256 blocks (16 rows each), 512 threads = 8 waves splitting the 1688 o-tiles
__global__ __launch_bounds__(512) void t3_fused(const __hip_bfloat16* __restrict__ mega,
        const __hip_bfloat16* __restrict__ w2b,   // [27008][32] bf16, zero-padded
        const int* __restrict__ targets,
        float* __restrict__ tgt_out, float* __restrict__ lse_out) {
    __shared__ int   relc[16];
    __shared__ float ttgt[16];
    __shared__ float wmm[8][16], wss[8][16];
    int rg = blockIdx.x;
    int tid = threadIdx.x;
    int wv = tid >> 6, lane = tid & 63;
    if (tid < 16) {
        int gr = rg * 16 + tid;
        int rel = 0;
        if (gr < NR) {
            int b = gr / (SS - 1), t = gr % (SS - 1);
            int lbl = targets[b * SS + t + 1];
            rel = lbl - 5000;
            rel = rel < 0 ? 0 : (rel > 26999 ? 26999 : rel);
        }
        relc[tid] = rel;
    }
    __syncthreads();
    int q = lane >> 4, cm = lane & 15;
    // A-frag (held across the whole o-loop): A[m=lane&15][k=q*8+j]
    bh8 af = *(const bh8*)(mega + (size_t)(rg * 16 + cm) * MC_LD + MC_P3 + q * 8);
    int rc[4];
    #pragma unroll
    for (int r = 0; r < 4; ++r) rc[r] = relc[q * 4 + r];
    float m[4], s[4];
    #pragma unroll
    for (int r = 0; r < 4; ++r) { m[r] = -1e30f; s[r] = 0.f; }
    for (int ot = wv; ot < 1688; ot += 8) {
        bh8 bf = *(const bh8*)(w2b + (size_t)(ot * 16 + cm) * 32 + q * 8);
        f32x4 c = __builtin_amdgcn_mfma_f32_16x16x32_bf16(af, bf, (f32x4){0.f, 0.f, 0.f, 0.f}, 0, 0, 0);
        int o = ot * 16 + cm;
        bool valid = o < 27000;
        #pragma unroll
        for (int r = 0; r < 4; ++r) {
            float v = c[r];
            if (o == rc[r]) ttgt[q * 4 + r] = v;   // exactly one writer per row
            float vv = valid ? v : -1e30f;
            float nm = fmaxf(m[r], vv);
            s[r] = s[r] * __expf(m[r] - nm) + __expf(vv - nm);
            m[r] = nm;
        }
    }
    // merge across the 16 lanes holding different cols of the same rows
    #pragma unroll
    for (int off = 1; off < 16; off <<= 1) {
        #pragma unroll
        for (int r = 0; r < 4; ++r) {
            float om = __shfl_xor(m[r], off, 64);
            float os = __shfl_xor(s[r], off, 64);
            float nm = fmaxf(m[r], om);
            s[r] = s[r] * __expf(m[r] - nm) + os * __expf(om - nm);
            m[r] = nm;
        }
    }
    if (cm == 0) {
        #pragma unroll
        for (int r = 0; r < 4; ++r) { wmm[wv][q * 4 + r] = m[r]; wss[wv][q * 4 + r] = s[r]; }
    }
    __syncthreads();
    if (tid < 16) {
        int gr = rg * 16 + tid;
        if (gr < NR) {
            float M = wmm[0][tid], S = wss[0][tid];
            #pragma unroll
            for (int w = 1; w < 8; ++w) {
                float om = wmm[w][tid], os = wss[w][tid];
                float nm = fmaxf(M, om);
                S = S * __expf(M - nm) + os * __expf(om - nm);
                M = nm;
            }
            lse_out[gr] = M + logf(S);
            tgt_out[gr] = ttgt[tid];
        }
    }
}

// ---------------- final: assemble per-row logprob, mean, negate ----------------
__global__ __launch_bounds__(256) void final_kernel(const float* __restrict__ aux,
        const int* __restrict__ targets,
        const float* __restrict__ tt0, const float* __restrict__ tl0,
        const float* __restrict__ tt1, const float* __restrict__ tl1,
        const float* __restrict__ tt2, const float* __restrict__ tl2,
        float* __restrict__ out) {
    float local = 0.f;
    for (int n = threadIdx.x; n < NR; n += 256) {
        int b = n / (SS - 1), t = n % (SS - 1);
        int lbl = targets[b * SS + t + 1];
        float lse = aux[n * 8 + 1];
        float o;
        if (lbl < 1000)      o = aux[n * 8 + 0] - lse;
        else if (lbl < 2000) o = (aux[n * 8 + 2] - lse) + (tt0[n] - tl0[n]);
        else if (lbl < 5000) o = (aux[n * 8 + 3] - lse) + (tt1[n] - tl1[n]);
        else                 o = (aux[n * 8 + 4] - lse) + (tt2[n] - tl2[n]);
        local += o;
    }
    float tot = block_sum256(local);
    if (threadIdx.x == 0) out[0] = -tot / (float)NR;
}

extern "C" void kernel_launch(void* const* d_in, const int* in_sizes, int n_in,
                              void* d_out, int out_size, void* d_ws, size_t ws_size,
                              hipStream_t stream) {
    const float* x      = (const float*)d_in[0];
    const int*   targets= (const int*)d_in[1];
    const float* gamma  = (const float*)d_in[2];
    const float* beta   = (const float*)d_in[3];
    const float* head_w = (const float*)d_in[4];
    const float* t1_w1  = (const float*)d_in[5];
    const float* t1_w2  = (const float*)d_in[6];
    const float* t2_w1  = (const float*)d_in[7];
    const float* t2_w2  = (const float*)d_in[8];
    const float* t3_w1  = (const float*)d_in[9];
    const float* t3_w2  = (const float*)d_in[10];
    (void)in_sizes; (void)n_in; (void)out_size; (void)ws_size;

    char* base = (char*)d_ws;
    size_t off = 0;
    auto ab = [&](size_t nbytes) { char* p = base + off; off += (nbytes + 15) & ~(size_t)15; return p; };
    __hip_bfloat16* h      = (__hip_bfloat16*)ab((size_t)NRP * DD * 2);          // 16.8 MB
    __hip_bfloat16* w1cat  = (__hip_bfloat16*)ab((size_t)MC_LD * DD * 2);        // 7.3 MB
    __hip_bfloat16* mega   = (__hip_bfloat16*)ab((size_t)NRP * MC_LD * 2);       // 14.7 MB
    __hip_bfloat16* t1w2b  = (__hip_bfloat16*)ab((size_t)1024 * 512 * 2);        // 1.0 MB
    __hip_bfloat16* C1     = (__hip_bfloat16*)ab((size_t)NRP * 1024 * 2);        // 8.4 MB
    __hip_bfloat16* t2w2b  = (__hip_bfloat16*)ab((size_t)3072 * 128 * 2);        // 0.8 MB
    __hip_bfloat16* C2     = (__hip_bfloat16*)ab((size_t)NRP * 3072 * 2);        // 25.2 MB
    __hip_bfloat16* w2b3   = (__hip_bfloat16*)ab((size_t)27008 * 32 * 2);        // 1.7 MB
    float* aux = (float*)ab((size_t)NRP * 8 * 4);
    float* tt0 = (float*)ab(NR * 4); float* tl0 = (float*)ab(NR * 4);
    float* tt1 = (float*)ab(NR * 4); float* tl1 = (float*)ab(NR * 4);
    float* tt2 = (float*)ab(NR * 4); float* tl2 = (float*)ab(NR * 4);

    auto cgrid = [](int n_tot) { return (n_tot / 4 + 255) / 256; };

    ln_kernel<<<NRP, 256, 0, stream>>>(x, gamma, beta, h);
    // weight casts into the concatenated / padded bf16 buffers
    cast_pad<<<cgrid(1024*2048), 256, 0, stream>>>(head_w, w1cat,              1003*2048, 1024*2048);
    cast_pad<<<cgrid(512*2048),  256, 0, stream>>>(t1_w1,  w1cat + 1024*2048,  512*2048,  512*2048);
    cast_pad<<<cgrid(128*2048),  256, 0, stream>>>(t2_w1,  w1cat + 1536*2048,  128*2048,  128*2048);
    cast_pad<<<cgrid(128*2048),  256, 0, stream>>>(t3_w1,  w1cat + 1664*2048,  32*2048,   128*2048);
    cast_pad<<<cgrid(1024*512),  256, 0, stream>>>(t1_w2,  t1w2b,              1000*512,  1024*512);
    cast_pad<<<cgrid(3072*128),  256, 0, stream>>>(t2_w2,  t2w2b,              3000*128,  3072*128);
    cast_pad<<<cgrid(27008*32),  256, 0, stream>>>(t3_w2,  w2b3,               27000*32,  27008*32);

    // mega GEMM: head logits + all 3 projections in one pass
    gemm_bf16<<<dim3(14, 32), 256, 0, stream>>>(h, DD, w1cat, mega, MC_LD, DD);
    // tail logit GEMMs (A = projection slices of mega-C)
    gemm_bf16<<<dim3(8, 32),  256, 0, stream>>>(mega + MC_P1, MC_LD, t1w2b, C1, 1024, 512);
    gemm_bf16<<<dim3(24, 32), 256, 0, stream>>>(mega + MC_P2, MC_LD, t2w2b, C2, 3072, 128);

    head_reduce<<<NR, 256, 0, stream>>>(mega, targets, aux);
    tail_reduce<<<NR, 256, 0, stream>>>(C1, 1024, 1000, 1000, targets, tt0, tl0);
    tail_reduce<<<NR, 256, 0, stream>>>(C2, 3072, 3000, 2000, targets, tt1, tl1);
    t3_fused<<<256, 512, 0, stream>>>(mega, w2b3, targets, tt2, tl2);
    final_kernel<<<1, 256, 0, stream>>>(aux, targets, tt0, tl0, tt1, tl1, tt2, tl2, (float*)d_out);
}

// Round 3
// 255.846 us; speedup vs baseline: 6.8785x; 1.3524x over previous
//
#include <hip/hip_runtime.h>
#include <hip/hip_bf16.h>
#include <math.h>

#define BB 2
#define SS 2048
#define DD 2048
#define NR (BB*(SS-1))      // 4094 valid rows
#define NRP 4096            // padded rows
// mega-C column layout (one GEMM produces head logits + all three projections)
#define MC_P1   1024
#define MC_P2   1536
#define MC_P3   1664
#define MC_LD   1792

#define L2E 1.4426950408889634f
#define LSE_SHIFT 4.0f
#define LSE_NC (-LSE_SHIFT * L2E)    // exp(v-SHIFT) == exp2(fma(v, L2E, NC))

typedef short  bh8   __attribute__((ext_vector_type(8)));   // 8 x bf16 (4 VGPRs)
typedef float  f32x4 __attribute__((ext_vector_type(4)));

__device__ inline float bfl(unsigned short b) { return __uint_as_float(((unsigned)b) << 16); }
__device__ inline float expsh(float v) {        // exp(v - LSE_SHIFT), 2 VALU
    return __builtin_amdgcn_exp2f(fmaf(v, L2E, LSE_NC));
}

// ---------------- block reduce (blockDim = 256) ----------------
__device__ inline float block_sum256(float v) {
    __shared__ float tmp[4];
    #pragma unroll
    for (int o = 32; o > 0; o >>= 1) v += __shfl_down(v, o, 64);
    int lane = threadIdx.x & 63, w = threadIdx.x >> 6;
    if (lane == 0) tmp[w] = v;
    __syncthreads();
    float r = tmp[0] + tmp[1] + tmp[2] + tmp[3];
    __syncthreads();
    return r;
}

// ---------------- LayerNorm -> bf16 h (rows NR..NRP-1 zeroed) ----------------
__global__ __launch_bounds__(256) void ln_kernel(const float* __restrict__ x,
        const float* __restrict__ gamma, const float* __restrict__ beta,
        __hip_bfloat16* __restrict__ h) {
    int n = blockIdx.x;                 // 0..NRP-1
    int tid = threadIdx.x;
    __hip_bfloat16* hr = h + (size_t)n * DD;
    if (n >= NR) {
        *(uint4*)(hr + tid * 8) = make_uint4(0, 0, 0, 0);
        return;
    }
    int b = n / (SS - 1), t = n % (SS - 1);
    const float4* xr = (const float4*)(x + (size_t)(b * SS + t) * DD);
    float4 a = xr[tid * 2];
    float4 c = xr[tid * 2 + 1];
    float sum = a.x + a.y + a.z + a.w + c.x + c.y + c.z + c.w;
    sum = block_sum256(sum);
    float mu = sum * (1.0f / DD);
    float d[8] = {a.x - mu, a.y - mu, a.z - mu, a.w - mu,
                  c.x - mu, c.y - mu, c.z - mu, c.w - mu};
    float sq = 0.f;
    #pragma unroll
    for (int i = 0; i < 8; ++i) sq += d[i] * d[i];
    sq = block_sum256(sq);
    float rstd = rsqrtf(sq * (1.0f / DD) + 1e-5f);
    const float4* g4 = (const float4*)gamma;
    const float4* be4 = (const float4*)beta;
    float4 g1 = g4[tid * 2], g2 = g4[tid * 2 + 1];
    float4 b1 = be4[tid * 2], b2 = be4[tid * 2 + 1];
    float gg[8] = {g1.x, g1.y, g1.z, g1.w, g2.x, g2.y, g2.z, g2.w};
    float bb[8] = {b1.x, b1.y, b1.z, b1.w, b2.x, b2.y, b2.z, b2.w};
    __align__(16) __hip_bfloat16 ob[8];
    #pragma unroll
    for (int i = 0; i < 8; ++i) ob[i] = __float2bfloat16(d[i] * rstd * gg[i] + bb[i]);
    *(uint4*)(hr + tid * 8) = *(uint4*)ob;
}

// ---------------- all weight casts in ONE launch ----------------
struct CastSegs {
    const float* src[7];
    __hip_bfloat16* dst[7];
    int n_src[7];        // all multiples of 4
    int n_tot[7];
    int b0[7];           // first block of each segment
};
__global__ __launch_bounds__(256) void cast_all(CastSegs sg) {
    int blk = blockIdx.x;
    int k = 0;
    #pragma unroll
    for (int i = 1; i < 7; ++i) if (blk >= sg.b0[i]) k = i;   // block-uniform
    int i4 = (blk - sg.b0[k]) * 1024 + threadIdx.x * 4;
    if (i4 >= sg.n_tot[k]) return;
    float4 v = make_float4(0.f, 0.f, 0.f, 0.f);
    if (i4 < sg.n_src[k]) v = *(const float4*)(sg.src[k] + i4);
    __align__(8) __hip_bfloat16 o[4] = {
        __float2bfloat16(v.x), __float2bfloat16(v.y),
        __float2bfloat16(v.z), __float2bfloat16(v.w)};
    *(uint2*)(sg.dst[k] + i4) = *(uint2*)o;
}

// ---------------- bf16 MFMA GEMM (m97 structure) ----------------
__global__ __launch_bounds__(256) void gemm_bf16(
        const __hip_bfloat16* __restrict__ A, int lda,
        const __hip_bfloat16* __restrict__ W,        // [Mpad][K], ldw == K
        __hip_bfloat16* __restrict__ C, int ldc,
        int K) {
    __shared__ __align__(16) __hip_bfloat16 As[128 * 32];
    __shared__ __align__(16) __hip_bfloat16 Ws[128 * 32];
    int tid = threadIdx.x;
    int wv = tid >> 6, lane = tid & 63;
    size_t row0 = (size_t)blockIdx.y * 128;
    size_t col0 = (size_t)blockIdx.x * 128;
    int wrow = (wv >> 1) * 64, wcol = (wv & 1) * 64;
    f32x4 acc[4][4];
    #pragma unroll
    for (int i = 0; i < 4; ++i)
        #pragma unroll
        for (int j = 0; j < 4; ++j) acc[i][j] = (f32x4){0.f, 0.f, 0.f, 0.f};

    int sr = lane >> 2;
    int sk = (lane & 3) * 8;
    int mrow = lane & 15;
    int q16 = (lane >> 4) * 16;

    for (int k0 = 0; k0 < K; k0 += 32) {
        __syncthreads();
        #pragma unroll
        for (int i = 0; i < 2; ++i) {
            int chunk = wv * 2 + i;
            int r = chunk * 16 + sr;
            const void* ga = A + (row0 + r) * lda + k0 + sk;
            const void* gw = W + (col0 + r) * (size_t)K + k0 + sk;
            void* la = (char*)As + chunk * 1024 + lane * 16;
            void* lw = (char*)Ws + chunk * 1024 + lane * 16;
            __builtin_amdgcn_global_load_lds(
                (const __attribute__((address_space(1))) void*)ga,
                (__attribute__((address_space(3))) void*)la, 16, 0, 0);
            __builtin_amdgcn_global_load_lds(
                (const __attribute__((address_space(1))) void*)gw,
                (__attribute__((address_space(3))) void*)lw, 16, 0, 0);
        }
        __syncthreads();
        bh8 af[4], bfr[4];
        #pragma unroll
        for (int t = 0; t < 4; ++t) {
            af[t]  = *(const bh8*)((const char*)As + (wrow + t * 16 + mrow) * 64 + q16);
            bfr[t] = *(const bh8*)((const char*)Ws + (wcol + t * 16 + mrow) * 64 + q16);
        }
        #pragma unroll
        for (int i = 0; i < 4; ++i)
            #pragma unroll
            for (int j = 0; j < 4; ++j)
                acc[i][j] = __builtin_amdgcn_mfma_f32_16x16x32_bf16(af[i], bfr[j], acc[i][j], 0, 0, 0);
    }
    int ccol = lane & 15;
    int crow = (lane >> 4) * 4;
    #pragma unroll
    for (int i = 0; i < 4; ++i) {
        size_t gr0 = row0 + wrow + i * 16 + crow;
        #pragma unroll
        for (int j = 0; j < 4; ++j) {
            size_t gc = col0 + wcol + j * 16 + ccol;
            #pragma unroll
            for (int r = 0; r < 4; ++r)
                C[(gr0 + r) * ldc + gc] = __float2bfloat16(acc[i][j][r]);
        }
    }
}

// ---------------- head: single-pass fixed-shift LSE over 1003 + gathers ----------------
__global__ __launch_bounds__(256) void head_reduce(const __hip_bfloat16* __restrict__ mega,
        const int* __restrict__ targets, float* __restrict__ aux) {
    int n = blockIdx.x;
    const __hip_bfloat16* lr = mega + (size_t)n * MC_LD;
    int tid = threadIdx.x;
    float s = 0.f;
    if (tid < 250) {                       // cols 0..999, 4 bf16 each
        uint2 u = *(const uint2*)(lr + tid * 4);
        s += expsh(bfl(u.x & 0xffff)) + expsh(bfl(u.x >> 16))
           + expsh(bfl(u.y & 0xffff)) + expsh(bfl(u.y >> 16));
    } else if (tid < 253) {                // cols 1000..1002
        s += expsh(bfl(((const unsigned short*)lr)[1000 + tid - 250]));
    }
    s = block_sum256(s);
    if (tid == 0) {
        int b = n / (SS - 1), t = n % (SS - 1);
        int lbl = targets[b * SS + t + 1];
        int ti = lbl < 1000 ? lbl : 999;
        aux[n * 8 + 0] = __bfloat162float(lr[ti]);
        aux[n * 8 + 1] = logf(s) + LSE_SHIFT;
        aux[n * 8 + 2] = __bfloat162float(lr[1000]);
        aux[n * 8 + 3] = __bfloat162float(lr[1001]);
        aux[n * 8 + 4] = __bfloat162float(lr[1002]);
    }
}

// ---------------- tail 1/2: single-pass LSE + target gather ----------------
__global__ __launch_bounds__(256) void tail_reduce(const __hip_bfloat16* __restrict__ logits,
        int ldc, int osz, int low, const int* __restrict__ targets,
        float* __restrict__ tgt_out, float* __restrict__ lse_out) {
    int n = blockIdx.x;
    const __hip_bfloat16* lr = logits + (size_t)n * ldc;
    int tid = threadIdx.x;
    float s = 0.f;
    int ng = osz >> 2;                     // osz % 4 == 0
    for (int g = tid; g < ng; g += 256) {
        uint2 u = *(const uint2*)(lr + g * 4);
        s += expsh(bfl(u.x & 0xffff)) + expsh(bfl(u.x >> 16))
           + expsh(bfl(u.y & 0xffff)) + expsh(bfl(u.y >> 16));
    }
    s = block_sum256(s);
    if (tid == 0) {
        int b = n / (SS - 1), t = n % (SS - 1);
        int lbl = targets[b * SS + t + 1];
        int rel = lbl - low;
        rel = rel < 0 ? 0 : (rel > osz - 1 ? osz - 1 : rel);
        tgt_out[n] = __bfloat162float(lr[rel]);
        lse_out[n] = logf(s) + LSE_SHIFT;
    }
}

// ---------------- tail 3 stage 1: MFMA + fixed-shift exp partial sums ----------------
// grid (128 rowgroups of 32, 8 col-splits), 256 thr = 4 waves. 1688 tiles of 16 cols.
__global__ __launch_bounds__(256) void t3_partial(const __hip_bfloat16* __restrict__ mega,
        const __hip_bfloat16* __restrict__ w2b,   // [27008][32] bf16, zero-padded
        float* __restrict__ pS) {                 // [4096][8] partial sums
    __shared__ float red[4][32];
    int rg = blockIdx.x;                  // 32 rows
    int cs = blockIdx.y;                  // col split
    int tid = threadIdx.x;
    int wv = tid >> 6, lane = tid & 63;
    int q = lane >> 4, cm = lane & 15;    // q: 0..3 (k-chunk / acc rows), cm: m or n index
    int row0 = rg * 32;
    // A-frags held in registers for the whole loop: A[m=cm][k=q*8+j]
    bh8 af0 = *(const bh8*)(mega + (size_t)(row0 + cm) * MC_LD + MC_P3 + q * 8);
    bh8 af1 = *(const bh8*)(mega + (size_t)(row0 + 16 + cm) * MC_LD + MC_P3 + q * 8);
    int tile0 = cs * 211, tile1 = tile0 + 211;    // 8*211 == 1688
    float s0[4] = {0.f, 0.f, 0.f, 0.f}, s1[4] = {0.f, 0.f, 0.f, 0.f};
    bh8 bf = *(const bh8*)(w2b + (size_t)((tile0 + wv) * 16 + cm) * 32 + q * 8);
    for (int ot = tile0 + wv; ot < tile1; ot += 4) {
        int otn = ot + 4;
        bh8 bfn = bf;
        if (otn < tile1)                   // prefetch next b-frag (hides L2 latency)
            bfn = *(const bh8*)(w2b + (size_t)(otn * 16 + cm) * 32 + q * 8);
        f32x4 c0 = __builtin_amdgcn_mfma_f32_16x16x32_bf16(af0, bf, (f32x4){0.f,0.f,0.f,0.f}, 0, 0, 0);
        f32x4 c1 = __builtin_amdgcn_mfma_f32_16x16x32_bf16(af1, bf, (f32x4){0.f,0.f,0.f,0.f}, 0, 0, 0);
        #pragma unroll
        for (int r = 0; r < 4; ++r) {
            s0[r] += expsh(c0[r]);
            s1[r] += expsh(c1[r]);
        }
        bf = bfn;
    }
    // reduce over the 16 cols held by lanes with same q (lane bits 0..3)
    #pragma unroll
    for (int off = 1; off < 16; off <<= 1) {
        #pragma unroll
        for (int r = 0; r < 4; ++r) {
            s0[r] += __shfl_xor(s0[r], off, 64);
            s1[r] += __shfl_xor(s1[r], off, 64);
        }
    }
    if (cm == 0) {                         // lanes 0,16,32,48: rows q*4+r
        #pragma unroll
        for (int r = 0; r < 4; ++r) {
            red[wv][q * 4 + r]      = s0[r];
            red[wv][16 + q * 4 + r] = s1[r];
        }
    }
    __syncthreads();
    if (tid < 32)
        pS[(size_t)(row0 + tid) * 8 + cs] = red[0][tid] + red[1][tid] + red[2][tid] + red[3][tid];
}

// ---------------- tail 3: per-row target logit (dot of 32) ----------------
__global__ __launch_bounds__(256) void t3_gather(const __hip_bfloat16* __restrict__ mega,
        const __hip_bfloat16* __restrict__ w2b, const int* __restrict__ targets,
        float* __restrict__ tt2) {
    int n = blockIdx.x * 256 + threadIdx.x;
    if (n >= NR) return;
    int b = n / (SS - 1), t = n % (SS - 1);
    int lbl = targets[b * SS + t + 1];
    int rel = lbl - 5000;
    rel = rel < 0 ? 0 : (rel > 26999 ? 26999 : rel);
    const unsigned short* pa = (const unsigned short*)(mega + (size_t)n * MC_LD + MC_P3);
    const unsigned short* pw = (const unsigned short*)(w2b + (size_t)rel * 32);
    float acc = 0.f;
    #pragma unroll
    for (int k = 0; k < 32; ++k) acc += bfl(pa[k]) * bfl(pw[k]);
    tt2[n] = acc;
}

// ---------------- final: assemble per-row logprob, mean, negate ----------------
__global__ __launch_bounds__(256) void final_kernel(const float* __restrict__ aux,
        const int* __restrict__ targets,
        const float* __restrict__ tt0, const float* __restrict__ tl0,
        const float* __restrict__ tt1, const float* __restrict__ tl1,
        const float* __restrict__ tt2, const float* __restrict__ pS3,
        float* __restrict__ out) {
    float pad_sub = 8.0f * __builtin_amdgcn_exp2f(LSE_NC);  // 8 zero-pad cols, exact
    float local = 0.f;
    for (int n = threadIdx.x; n < NR; n += 256) {
        int b = n / (SS - 1), t = n % (SS - 1);
        int lbl = targets[b * SS + t + 1];
        float lse = aux[n * 8 + 1];
        float o;
        if (lbl < 1000)      o = aux[n * 8 + 0] - lse;
        else if (lbl < 2000) o = (aux[n * 8 + 2] - lse) + (tt0[n] - tl0[n]);
        else if (lbl < 5000) o = (aux[n * 8 + 3] - lse) + (tt1[n] - tl1[n]);
        else {
            float S3 = 0.f;
            #pragma unroll
            for (int c = 0; c < 8; ++c) S3 += pS3[n * 8 + c];
            float tl2 = logf(S3 - pad_sub) + LSE_SHIFT;
            o = (aux[n * 8 + 4] - lse) + (tt2[n] - tl2);
        }
        local += o;
    }
    float tot = block_sum256(local);
    if (threadIdx.x == 0) out[0] = -tot / (float)NR;
}

extern "C" void kernel_launch(void* const* d_in, const int* in_sizes, int n_in,
                              void* d_out, int out_size, void* d_ws, size_t ws_size,
                              hipStream_t stream) {
    const float* x      = (const float*)d_in[0];
    const int*   targets= (const int*)d_in[1];
    const float* gamma  = (const float*)d_in[2];
    const float* beta   = (const float*)d_in[3];
    const float* head_w = (const float*)d_in[4];
    const float* t1_w1  = (const float*)d_in[5];
    const float* t1_w2  = (const float*)d_in[6];
    const float* t2_w1  = (const float*)d_in[7];
    const float* t2_w2  = (const float*)d_in[8];
    const float* t3_w1  = (const float*)d_in[9];
    const float* t3_w2  = (const float*)d_in[10];
    (void)in_sizes; (void)n_in; (void)out_size; (void)ws_size;

    char* base = (char*)d_ws;
    size_t off = 0;
    auto ab = [&](size_t nbytes) { char* p = base + off; off += (nbytes + 15) & ~(size_t)15; return p; };
    __hip_bfloat16* h      = (__hip_bfloat16*)ab((size_t)NRP * DD * 2);
    __hip_bfloat16* w1cat  = (__hip_bfloat16*)ab((size_t)MC_LD * DD * 2);
    __hip_bfloat16* mega   = (__hip_bfloat16*)ab((size_t)NRP * MC_LD * 2);
    __hip_bfloat16* t1w2b  = (__hip_bfloat16*)ab((size_t)1024 * 512 * 2);
    __hip_bfloat16* C1     = (__hip_bfloat16*)ab((size_t)NRP * 1024 * 2);
    __hip_bfloat16* t2w2b  = (__hip_bfloat16*)ab((size_t)3072 * 128 * 2);
    __hip_bfloat16* C2     = (__hip_bfloat16*)ab((size_t)NRP * 3072 * 2);
    __hip_bfloat16* w2b3   = (__hip_bfloat16*)ab((size_t)27008 * 32 * 2);
    float* aux = (float*)ab((size_t)NRP * 8 * 4);
    float* pS3 = (float*)ab((size_t)NRP * 8 * 4);
    float* tt0 = (float*)ab(NR * 4); float* tl0 = (float*)ab(NR * 4);
    float* tt1 = (float*)ab(NR * 4); float* tl1 = (float*)ab(NR * 4);
    float* tt2 = (float*)ab(NR * 4);

    ln_kernel<<<NRP, 256, 0, stream>>>(x, gamma, beta, h);

    CastSegs sg;
    const float* srcs[7] = {head_w, t1_w1, t2_w1, t3_w1, t1_w2, t2_w2, t3_w2};
    __hip_bfloat16* dsts[7] = {w1cat, w1cat + 1024*2048, w1cat + 1536*2048,
                               w1cat + 1664*2048, t1w2b, t2w2b, w2b3};
    int nsrc[7] = {1003*2048, 512*2048, 128*2048, 32*2048, 1000*512, 3000*128, 27000*32};
    int ntot[7] = {1024*2048, 512*2048, 128*2048, 128*2048, 1024*512, 3072*128, 27008*32};
    int blk = 0;
    for (int i = 0; i < 7; ++i) {
        sg.src[i] = srcs[i]; sg.dst[i] = dsts[i];
        sg.n_src[i] = nsrc[i]; sg.n_tot[i] = ntot[i];
        sg.b0[i] = blk;
        blk += (ntot[i] + 1023) / 1024;
    }
    cast_all<<<blk, 256, 0, stream>>>(sg);

    gemm_bf16<<<dim3(14, 32), 256, 0, stream>>>(h, DD, w1cat, mega, MC_LD, DD);
    gemm_bf16<<<dim3(8, 32),  256, 0, stream>>>(mega + MC_P1, MC_LD, t1w2b, C1, 1024, 512);
    gemm_bf16<<<dim3(24, 32), 256, 0, stream>>>(mega + MC_P2, MC_LD, t2w2b, C2, 3072, 128);

    head_reduce<<<NR, 256, 0, stream>>>(mega, targets, aux);
    tail_reduce<<<NR, 256, 0, stream>>>(C1, 1024, 1000, 1000, targets, tt0, tl0);
    tail_reduce<<<NR, 256, 0, stream>>>(C2, 3072, 3000, 2000, targets, tt1, tl1);
    t3_partial<<<dim3(128, 8), 256, 0, stream>>>(mega, w2b3, pS3);
    t3_gather<<<16, 256, 0, stream>>>(mega, w2b3, targets, tt2);
    final_kernel<<<1, 256, 0, stream>>>(aux, targets, tt0, tl0, tt1, tl1, tt2, pS3, (float*)d_out);
}

// Round 4
// 213.100 us; speedup vs baseline: 8.2582x; 1.2006x over previous
//
#include <hip/hip_runtime.h>
#include <hip/hip_bf16.h>
#include <math.h>

#define BB 2
#define SS 2048
#define DD 2048
#define NR (BB*(SS-1))      // 4094 valid rows
#define NRP 4096            // padded rows
#define MT_LD 768           // compact mega-T layout: [p1 512 | p2 128 | p3 32 | pad]
#define MT_P2 512
#define MT_P3 640

#define L2E 1.4426950408889634f
#define LSE_SHIFT 4.0f
#define LSE_NC (-LSE_SHIFT * L2E)

typedef short  bh8   __attribute__((ext_vector_type(8)));
typedef float  f32x4 __attribute__((ext_vector_type(4)));

__device__ inline float bfl(unsigned short b) { return __uint_as_float(((unsigned)b) << 16); }
__device__ inline float expsh(float v) {        // exp(v - LSE_SHIFT): 2 VALU
    return __builtin_amdgcn_exp2f(fmaf(v, L2E, LSE_NC));
}

__device__ inline float block_sum256(float v) {
    __shared__ float tmp[4];
    #pragma unroll
    for (int o = 32; o > 0; o >>= 1) v += __shfl_down(v, o, 64);
    int lane = threadIdx.x & 63, w = threadIdx.x >> 6;
    if (lane == 0) tmp[w] = v;
    __syncthreads();
    float r = tmp[0] + tmp[1] + tmp[2] + tmp[3];
    __syncthreads();
    return r;
}

// ================= stage A: LN + weight casts + index/zero init, ONE launch =================
struct CastSegs {
    const float* src[7];
    __hip_bfloat16* dst[7];
    int n_src[7];
    int n_tot[7];
    int b0[7];
};
struct AParams {
    const float* x; const float* gamma; const float* beta;
    __hip_bfloat16* h;
    CastSegs sg; int castBlocks;
    const int* targets;
    int *relH, *rel1, *rel2, *rel3;
    float *S0, *S1, *S2, *out;
};

__global__ __launch_bounds__(256) void stageA(AParams p) {
    int blk = blockIdx.x, tid = threadIdx.x;
    if (blk < NRP) {                                   // ---- LayerNorm role ----
        int n = blk;
        __hip_bfloat16* hr = p.h + (size_t)n * DD;
        if (n >= NR) { *(uint4*)(hr + tid * 8) = make_uint4(0,0,0,0); return; }
        int b = n / (SS - 1), t = n % (SS - 1);
        const float4* xr = (const float4*)(p.x + (size_t)(b * SS + t) * DD);
        float4 a = xr[tid * 2];
        float4 c = xr[tid * 2 + 1];
        float sum = a.x + a.y + a.z + a.w + c.x + c.y + c.z + c.w;
        sum = block_sum256(sum);
        float mu = sum * (1.0f / DD);
        float d[8] = {a.x-mu, a.y-mu, a.z-mu, a.w-mu, c.x-mu, c.y-mu, c.z-mu, c.w-mu};
        float sq = 0.f;
        #pragma unroll
        for (int i = 0; i < 8; ++i) sq += d[i] * d[i];
        sq = block_sum256(sq);
        float rstd = rsqrtf(sq * (1.0f / DD) + 1e-5f);
        const float4* g4 = (const float4*)p.gamma;
        const float4* be4 = (const float4*)p.beta;
        float4 g1 = g4[tid*2], g2 = g4[tid*2+1];
        float4 b1 = be4[tid*2], b2 = be4[tid*2+1];
        float gg[8] = {g1.x,g1.y,g1.z,g1.w,g2.x,g2.y,g2.z,g2.w};
        float bb[8] = {b1.x,b1.y,b1.z,b1.w,b2.x,b2.y,b2.z,b2.w};
        __align__(16) __hip_bfloat16 ob[8];
        #pragma unroll
        for (int i = 0; i < 8; ++i) ob[i] = __float2bfloat16(d[i] * rstd * gg[i] + bb[i]);
        *(uint4*)(hr + tid * 8) = *(uint4*)ob;
        return;
    }
    blk -= NRP;
    if (blk < p.castBlocks) {                          // ---- weight cast role ----
        int k = 0;
        #pragma unroll
        for (int i = 1; i < 7; ++i) if (blk >= p.sg.b0[i]) k = i;
        int i4 = (blk - p.sg.b0[k]) * 1024 + tid * 4;
        if (i4 >= p.sg.n_tot[k]) return;
        float4 v = make_float4(0.f,0.f,0.f,0.f);
        if (i4 < p.sg.n_src[k]) v = *(const float4*)(p.sg.src[k] + i4);
        __align__(8) __hip_bfloat16 o[4] = {
            __float2bfloat16(v.x), __float2bfloat16(v.y),
            __float2bfloat16(v.z), __float2bfloat16(v.w)};
        *(uint2*)(p.sg.dst[k] + i4) = *(uint2*)o;
        return;
    }
    blk -= p.castBlocks;                               // ---- init role (16 blocks) ----
    int n = blk * 256 + tid;
    if (n >= NRP) return;
    int lbl = -1;
    if (n < NR) {
        int b = n / (SS - 1), t = n % (SS - 1);
        lbl = p.targets[b * SS + t + 1];
    }
    bool v = n < NR;
    p.relH[n] = v ? (lbl < 1000 ? lbl : 999) : -1;
    int r1 = lbl - 1000;  p.rel1[n] = v ? (r1 < 0 ? 0 : (r1 > 999   ? 999   : r1)) : -1;
    int r2 = lbl - 2000;  p.rel2[n] = v ? (r2 < 0 ? 0 : (r2 > 2999  ? 2999  : r2)) : -1;
    int r3 = lbl - 5000;  p.rel3[n] = v ? (r3 < 0 ? 0 : (r3 > 26999 ? 26999 : r3)) : -1;
    p.S0[n] = 0.f; p.S1[n] = 0.f; p.S2[n] = 0.f;
    if (n == 0) p.out[0] = 0.f;
}

// ================= stage B: mega GEMM, 64x128 tile, head-LSE fused epilogue =================
// grid dim3(14, 64); bx<8 => head cols (epilogue only, no store); bx>=8 => store compact megaT
__global__ __launch_bounds__(256) void mega_gemm(
        const __hip_bfloat16* __restrict__ A,          // h [4096][2048]
        const __hip_bfloat16* __restrict__ W,          // w1cat [1792][2048]
        __hip_bfloat16* __restrict__ megaT,            // [4096][768]
        const int* __restrict__ relH,
        float* __restrict__ S0, float* __restrict__ aux) {
    __shared__ __align__(16) __hip_bfloat16 As[64 * 32];
    __shared__ __align__(16) __hip_bfloat16 Ws[128 * 32];
    int tid = threadIdx.x, wv = tid >> 6, lane = tid & 63;
    int row0 = blockIdx.y * 64, col0 = blockIdx.x * 128;
    int wrow = (wv >> 1) * 32, wcol = (wv & 1) * 64;
    f32x4 acc[2][4];
    #pragma unroll
    for (int i = 0; i < 2; ++i)
        #pragma unroll
        for (int j = 0; j < 4; ++j) acc[i][j] = (f32x4){0.f,0.f,0.f,0.f};
    int sr = lane >> 2, sk = (lane & 3) * 8, mrow = lane & 15, q16 = (lane >> 4) * 16;

    for (int k0 = 0; k0 < DD; k0 += 32) {
        __syncthreads();
        #pragma unroll
        for (int i = 0; i < 3; ++i) {                  // 12 chunks, 3 per wave
            int c = wv * 3 + i;
            const __hip_bfloat16* gsrc;
            char* ldst;
            if (c < 4) {
                gsrc = A + (size_t)(row0 + c * 16 + sr) * DD + k0 + sk;
                ldst = (char*)As + c * 1024 + lane * 16;
            } else {
                int cw = c - 4;
                gsrc = W + (size_t)(col0 + cw * 16 + sr) * DD + k0 + sk;
                ldst = (char*)Ws + cw * 1024 + lane * 16;
            }
            __builtin_amdgcn_global_load_lds(
                (const __attribute__((address_space(1))) void*)gsrc,
                (__attribute__((address_space(3))) void*)ldst, 16, 0, 0);
        }
        __syncthreads();
        bh8 af[2], bfr[4];
        #pragma unroll
        for (int t = 0; t < 2; ++t)
            af[t] = *(const bh8*)((const char*)As + (wrow + t*16 + mrow) * 64 + q16);
        #pragma unroll
        for (int t = 0; t < 4; ++t)
            bfr[t] = *(const bh8*)((const char*)Ws + (wcol + t*16 + mrow) * 64 + q16);
        #pragma unroll
        for (int i = 0; i < 2; ++i)
            #pragma unroll
            for (int j = 0; j < 4; ++j)
                acc[i][j] = __builtin_amdgcn_mfma_f32_16x16x32_bf16(af[i], bfr[j], acc[i][j], 0, 0, 0);
    }
    int ccol = lane & 15, g = lane >> 4;
    if (blockIdx.x < 8) {                              // head: fused LSE + gathers, no store
        int grs[2][4], rh[2][4];
        float p[2][4];
        #pragma unroll
        for (int i = 0; i < 2; ++i)
            #pragma unroll
            for (int r = 0; r < 4; ++r) {
                grs[i][r] = row0 + wrow + i*16 + g*4 + r;
                rh[i][r] = relH[grs[i][r]];
                p[i][r] = 0.f;
            }
        #pragma unroll
        for (int i = 0; i < 2; ++i)
            #pragma unroll
            for (int j = 0; j < 4; ++j) {
                int gc = col0 + wcol + j*16 + ccol;
                bool inr = gc < 1003;
                #pragma unroll
                for (int r = 0; r < 4; ++r) {
                    float v = acc[i][j][r];
                    int gr = grs[i][r];
                    if (gc == rh[i][r]) aux[gr*8 + 0] = v;
                    if (gc >= 1000 && gc < 1003) aux[gr*8 + 2 + (gc - 1000)] = v;
                    p[i][r] += inr ? expsh(v) : 0.f;
                }
            }
        #pragma unroll
        for (int off = 1; off < 16; off <<= 1)
            #pragma unroll
            for (int i = 0; i < 2; ++i)
                #pragma unroll
                for (int r = 0; r < 4; ++r) p[i][r] += __shfl_xor(p[i][r], off, 64);
        if (ccol == 0)
            #pragma unroll
            for (int i = 0; i < 2; ++i)
                #pragma unroll
                for (int r = 0; r < 4; ++r) atomicAdd(&S0[grs[i][r]], p[i][r]);
    } else {                                           // projection cols: store compact
        int cb = col0 - 1024 + wcol;
        #pragma unroll
        for (int i = 0; i < 2; ++i)
            #pragma unroll
            for (int j = 0; j < 4; ++j)
                #pragma unroll
                for (int r = 0; r < 4; ++r)
                    megaT[(size_t)(row0 + wrow + i*16 + g*4 + r) * MT_LD + cb + j*16 + ccol]
                        = __float2bfloat16(acc[i][j][r]);
    }
}

// ================= stage C device parts =================
// tail GEMM 64x128 with fused LSE epilogue (no logit store)
__device__ void tail_gemm(const __hip_bfloat16* A, int lda,
        const __hip_bfloat16* W, int K, int bx, int by, int validCols,
        const int* rel, float* S, float* tgt, char* sm) {
    __hip_bfloat16* As = (__hip_bfloat16*)sm;          // 4 KB
    __hip_bfloat16* Ws = (__hip_bfloat16*)(sm + 4096); // 8 KB
    int tid = threadIdx.x, wv = tid >> 6, lane = tid & 63;
    int row0 = by * 64, col0 = bx * 128;
    int wrow = (wv >> 1) * 32, wcol = (wv & 1) * 64;
    f32x4 acc[2][4];
    #pragma unroll
    for (int i = 0; i < 2; ++i)
        #pragma unroll
        for (int j = 0; j < 4; ++j) acc[i][j] = (f32x4){0.f,0.f,0.f,0.f};
    int sr = lane >> 2, sk = (lane & 3) * 8, mrow = lane & 15, q16 = (lane >> 4) * 16;

    for (int k0 = 0; k0 < K; k0 += 32) {
        __syncthreads();
        #pragma unroll
        for (int i = 0; i < 3; ++i) {
            int c = wv * 3 + i;
            const __hip_bfloat16* gsrc;
            char* ldst;
            if (c < 4) {
                gsrc = A + (size_t)(row0 + c * 16 + sr) * lda + k0 + sk;
                ldst = (char*)As + c * 1024 + lane * 16;
            } else {
                int cw = c - 4;
                gsrc = W + (size_t)(col0 + cw * 16 + sr) * K + k0 + sk;
                ldst = (char*)Ws + cw * 1024 + lane * 16;
            }
            __builtin_amdgcn_global_load_lds(
                (const __attribute__((address_space(1))) void*)gsrc,
                (__attribute__((address_space(3))) void*)ldst, 16, 0, 0);
        }
        __syncthreads();
        bh8 af[2], bfr[4];
        #pragma unroll
        for (int t = 0; t < 2; ++t)
            af[t] = *(const bh8*)((const char*)As + (wrow + t*16 + mrow) * 64 + q16);
        #pragma unroll
        for (int t = 0; t < 4; ++t)
            bfr[t] = *(const bh8*)((const char*)Ws + (wcol + t*16 + mrow) * 64 + q16);
        #pragma unroll
        for (int i = 0; i < 2; ++i)
            #pragma unroll
            for (int j = 0; j < 4; ++j)
                acc[i][j] = __builtin_amdgcn_mfma_f32_16x16x32_bf16(af[i], bfr[j], acc[i][j], 0, 0, 0);
    }
    int ccol = lane & 15, g = lane >> 4;
    int grs[2][4], rh[2][4];
    float p[2][4];
    #pragma unroll
    for (int i = 0; i < 2; ++i)
        #pragma unroll
        for (int r = 0; r < 4; ++r) {
            grs[i][r] = row0 + wrow + i*16 + g*4 + r;
            rh[i][r] = rel[grs[i][r]];
            p[i][r] = 0.f;
        }
    #pragma unroll
    for (int i = 0; i < 2; ++i)
        #pragma unroll
        for (int j = 0; j < 4; ++j) {
            int gc = col0 + wcol + j*16 + ccol;
            bool inr = gc < validCols;
            #pragma unroll
            for (int r = 0; r < 4; ++r) {
                float v = acc[i][j][r];
                if (gc == rh[i][r]) tgt[grs[i][r]] = v;
                p[i][r] += inr ? expsh(v) : 0.f;
            }
        }
    #pragma unroll
    for (int off = 1; off < 16; off <<= 1)
        #pragma unroll
        for (int i = 0; i < 2; ++i)
            #pragma unroll
            for (int r = 0; r < 4; ++r) p[i][r] += __shfl_xor(p[i][r], off, 64);
    if (ccol == 0)
        #pragma unroll
        for (int i = 0; i < 2; ++i)
            #pragma unroll
            for (int r = 0; r < 4; ++r) atomicAdd(&S[grs[i][r]], p[i][r]);
}

__device__ void t3_partial_body(const __hip_bfloat16* megaT,
        const __hip_bfloat16* w2b, float* pS, int idx, int tid, float* red /*[4][32]*/) {
    int rg = idx >> 3, cs = idx & 7;
    int wv = tid >> 6, lane = tid & 63;
    int q = lane >> 4, cm = lane & 15;
    int row0 = rg * 32;
    bh8 af0 = *(const bh8*)(megaT + (size_t)(row0 + cm) * MT_LD + MT_P3 + q * 8);
    bh8 af1 = *(const bh8*)(megaT + (size_t)(row0 + 16 + cm) * MT_LD + MT_P3 + q * 8);
    int tile0 = cs * 211, tile1 = tile0 + 211;
    float s0[4] = {0,0,0,0}, s1[4] = {0,0,0,0};
    bh8 bf = *(const bh8*)(w2b + (size_t)((tile0 + wv) * 16 + cm) * 32 + q * 8);
    for (int ot = tile0 + wv; ot < tile1; ot += 4) {
        int otn = ot + 4;
        bh8 bfn = bf;
        if (otn < tile1)
            bfn = *(const bh8*)(w2b + (size_t)(otn * 16 + cm) * 32 + q * 8);
        f32x4 c0 = __builtin_amdgcn_mfma_f32_16x16x32_bf16(af0, bf, (f32x4){0,0,0,0}, 0, 0, 0);
        f32x4 c1 = __builtin_amdgcn_mfma_f32_16x16x32_bf16(af1, bf, (f32x4){0,0,0,0}, 0, 0, 0);
        #pragma unroll
        for (int r = 0; r < 4; ++r) { s0[r] += expsh(c0[r]); s1[r] += expsh(c1[r]); }
        bf = bfn;
    }
    #pragma unroll
    for (int off = 1; off < 16; off <<= 1)
        #pragma unroll
        for (int r = 0; r < 4; ++r) {
            s0[r] += __shfl_xor(s0[r], off, 64);
            s1[r] += __shfl_xor(s1[r], off, 64);
        }
    if (cm == 0)
        #pragma unroll
        for (int r = 0; r < 4; ++r) {
            red[wv * 32 + q * 4 + r]      = s0[r];
            red[wv * 32 + 16 + q * 4 + r] = s1[r];
        }
    __syncthreads();
    if (tid < 32)
        pS[(size_t)(row0 + tid) * 8 + cs] = red[tid] + red[32 + tid] + red[64 + tid] + red[96 + tid];
}

__device__ void t3_gather_body(const __hip_bfloat16* megaT, const __hip_bfloat16* w2b,
        const int* rel3, float* tt2, int idx, int tid) {
    int n = idx * 256 + tid;
    if (n >= NR) return;
    int rc = rel3[n];
    const unsigned short* pa = (const unsigned short*)(megaT + (size_t)n * MT_LD + MT_P3);
    const unsigned short* pw = (const unsigned short*)(w2b + (size_t)rc * 32);
    float acc = 0.f;
    #pragma unroll
    for (int k = 0; k < 32; ++k) acc += bfl(pa[k]) * bfl(pw[k]);
    tt2[n] = acc;
}

// ================= stage C: fat kernel =================
#define NT3 1024
#define NT1 512
#define NT2 1536
__global__ __launch_bounds__(256) void fatC(const __hip_bfloat16* __restrict__ megaT,
        const __hip_bfloat16* __restrict__ t1w2b, const __hip_bfloat16* __restrict__ t2w2b,
        const __hip_bfloat16* __restrict__ w2b3,
        const int* __restrict__ rel1, const int* __restrict__ rel2, const int* __restrict__ rel3,
        float* __restrict__ S1, float* __restrict__ S2, float* __restrict__ pS3,
        float* __restrict__ tt0, float* __restrict__ tt1, float* __restrict__ tt2) {
    __shared__ __align__(16) char sm[12288];
    int idx = blockIdx.x, tid = threadIdx.x;
    if (idx < NT3) { t3_partial_body(megaT, w2b3, pS3, idx, tid, (float*)sm); return; }
    idx -= NT3;
    if (idx < NT1) { tail_gemm(megaT, MT_LD, t1w2b, 512, idx % 8, idx / 8, 1000, rel1, S1, tt0, sm); return; }
    idx -= NT1;
    if (idx < NT2) { tail_gemm(megaT + MT_P2, MT_LD, t2w2b, 128, idx % 24, idx / 24, 3000, rel2, S2, tt1, sm); return; }
    idx -= NT2;
    t3_gather_body(megaT, w2b3, rel3, tt2, idx, tid);
}

// ================= stage D: final assembly =================
__global__ __launch_bounds__(256) void final_kernel(const float* __restrict__ aux,
        const int* __restrict__ targets,
        const float* __restrict__ S0, const float* __restrict__ S1, const float* __restrict__ S2,
        const float* __restrict__ pS3,
        const float* __restrict__ tt0, const float* __restrict__ tt1, const float* __restrict__ tt2,
        float* __restrict__ out) {
    int n = blockIdx.x * 256 + threadIdx.x;
    float local = 0.f;
    if (n < NR) {
        int b = n / (SS - 1), t = n % (SS - 1);
        int lbl = targets[b * SS + t + 1];
        float lse = logf(S0[n]) + LSE_SHIFT;
        float o;
        if (lbl < 1000)      o = aux[n*8 + 0] - lse;
        else if (lbl < 2000) o = (aux[n*8 + 2] - lse) + (tt0[n] - (logf(S1[n]) + LSE_SHIFT));
        else if (lbl < 5000) o = (aux[n*8 + 3] - lse) + (tt1[n] - (logf(S2[n]) + LSE_SHIFT));
        else {
            float S3 = 0.f;
            #pragma unroll
            for (int c = 0; c < 8; ++c) S3 += pS3[n*8 + c];
            S3 -= 8.0f * __builtin_amdgcn_exp2f(LSE_NC);       // exact pad-col correction
            o = (aux[n*8 + 4] - lse) + (tt2[n] - (logf(S3) + LSE_SHIFT));
        }
        local = o;
    }
    local = block_sum256(local);
    if (threadIdx.x == 0) atomicAdd(out, -local / (float)NR);
}

extern "C" void kernel_launch(void* const* d_in, const int* in_sizes, int n_in,
                              void* d_out, int out_size, void* d_ws, size_t ws_size,
                              hipStream_t stream) {
    const float* x      = (const float*)d_in[0];
    const int*   targets= (const int*)d_in[1];
    const float* gamma  = (const float*)d_in[2];
    const float* beta   = (const float*)d_in[3];
    const float* head_w = (const float*)d_in[4];
    const float* t1_w1  = (const float*)d_in[5];
    const float* t1_w2  = (const float*)d_in[6];
    const float* t2_w1  = (const float*)d_in[7];
    const float* t2_w2  = (const float*)d_in[8];
    const float* t3_w1  = (const float*)d_in[9];
    const float* t3_w2  = (const float*)d_in[10];
    (void)in_sizes; (void)n_in; (void)out_size; (void)ws_size;

    char* base = (char*)d_ws;
    size_t off = 0;
    auto ab = [&](size_t nbytes) { char* p = base + off; off += (nbytes + 15) & ~(size_t)15; return p; };
    __hip_bfloat16* h      = (__hip_bfloat16*)ab((size_t)NRP * DD * 2);       // 16.8 MB
    __hip_bfloat16* w1cat  = (__hip_bfloat16*)ab((size_t)1792 * DD * 2);      // 7.3 MB
    __hip_bfloat16* megaT  = (__hip_bfloat16*)ab((size_t)NRP * MT_LD * 2);    // 6.3 MB
    __hip_bfloat16* t1w2b  = (__hip_bfloat16*)ab((size_t)1024 * 512 * 2);
    __hip_bfloat16* t2w2b  = (__hip_bfloat16*)ab((size_t)3072 * 128 * 2);
    __hip_bfloat16* w2b3   = (__hip_bfloat16*)ab((size_t)27008 * 32 * 2);
    float* aux = (float*)ab((size_t)NRP * 8 * 4);
    float* pS3 = (float*)ab((size_t)NRP * 8 * 4);
    float* S0  = (float*)ab(NRP * 4);
    float* S1  = (float*)ab(NRP * 4);
    float* S2  = (float*)ab(NRP * 4);
    int* relH  = (int*)ab(NRP * 4);
    int* rel1  = (int*)ab(NRP * 4);
    int* rel2  = (int*)ab(NRP * 4);
    int* rel3  = (int*)ab(NRP * 4);
    float* tt0 = (float*)ab(NRP * 4);
    float* tt1 = (float*)ab(NRP * 4);
    float* tt2 = (float*)ab(NRP * 4);

    AParams p;
    p.x = x; p.gamma = gamma; p.beta = beta; p.h = h;
    p.targets = targets;
    p.relH = relH; p.rel1 = rel1; p.rel2 = rel2; p.rel3 = rel3;
    p.S0 = S0; p.S1 = S1; p.S2 = S2; p.out = (float*)d_out;
    const float* srcs[7] = {head_w, t1_w1, t2_w1, t3_w1, t1_w2, t2_w2, t3_w2};
    __hip_bfloat16* dsts[7] = {w1cat, w1cat + 1024*2048, w1cat + 1536*2048,
                               w1cat + 1664*2048, t1w2b, t2w2b, w2b3};
    int nsrc[7] = {1003*2048, 512*2048, 128*2048, 32*2048, 1000*512, 3000*128, 27000*32};
    int ntot[7] = {1024*2048, 512*2048, 128*2048, 128*2048, 1024*512, 3072*128, 27008*32};
    int blk = 0;
    for (int i = 0; i < 7; ++i) {
        p.sg.src[i] = srcs[i]; p.sg.dst[i] = dsts[i];
        p.sg.n_src[i] = nsrc[i]; p.sg.n_tot[i] = ntot[i];
        p.sg.b0[i] = blk;
        blk += (ntot[i] + 1023) / 1024;
    }
    p.castBlocks = blk;

    stageA<<<NRP + blk + 16, 256, 0, stream>>>(p);
    mega_gemm<<<dim3(14, 64), 256, 0, stream>>>(h, w1cat, megaT, relH, S0, aux);
    fatC<<<NT3 + NT1 + NT2 + 16, 256, 0, stream>>>(megaT, t1w2b, t2w2b, w2b3,
            rel1, rel2, rel3, S1, S2, pS3, tt0, tt1, tt2);
    final_kernel<<<16, 256, 0, stream>>>(aux, targets, S0, S1, S2, pS3, tt0, tt1, tt2, (float*)d_out);
}